// Round 3
// baseline (110.528 us; speedup 1.0000x reference)
//
#include <hip/hip_runtime.h>
#include <cstdint>
#include <cstddef>

#define BATCH 64
#define PRI   8732
#define NCLS  81
#define NEGPOS 3
#define NTOT  (BATCH * PRI)          // 558848
#define PPB   64                     // priors per k_lse block
#define NBLK1 (NTOT / PPB)           // 8732 exactly
#define LDSP  84                     // padded floats per prior (336 B, 16B-mult)

__device__ __forceinline__ unsigned keymap(float f) {
    unsigned u = __float_as_uint(f);
    return (u & 0x80000000u) ? ~u : (u | 0x80000000u);
}

// ---------------------------------------------------------------------------
// Kernel 1: 256 threads / 64 priors per block. Coalesced float4 global loads
// into padded LDS tile; 4 threads per prior run online softmax on aligned LDS
// float4s, merge via 2 shfl_xor. Writes keymapped bg keys (positives -> 0),
// accumulates positive-ce and smooth-L1 into per-block partials.
// ---------------------------------------------------------------------------
__global__ __launch_bounds__(256) void k_lse(const float* __restrict__ conf,
                                             const int* __restrict__ labels,
                                             const float* __restrict__ ploc,
                                             const float* __restrict__ gloc,
                                             unsigned* __restrict__ keysg,
                                             float* __restrict__ cepart,
                                             float* __restrict__ slpart) {
    __shared__ float lds[PPB * LDSP];          // 21504 B
    __shared__ float red0[4], red1[4];
    const int t = threadIdx.x;
    const int b = blockIdx.x;

    // ---- stage: 1296 coalesced float4 loads, scatter into padded LDS rows
    const float4* g4 = reinterpret_cast<const float4*>(conf + (size_t)b * (PPB * NCLS));
#pragma unroll
    for (int kk = 0; kk < 6; ++kk) {
        const int i = t + 256 * kk;
        if (i < (PPB * NCLS / 4)) {            // 1296
            const float4 v = g4[i];
            const unsigned f = 4u * (unsigned)i;
            unsigned q = f / (unsigned)NCLS;   // magic-mul
            unsigned r = f - q * (unsigned)NCLS;
            lds[q * LDSP + r] = v.x;
            if (++r == NCLS) { r = 0; ++q; } lds[q * LDSP + r] = v.y;
            if (++r == NCLS) { r = 0; ++q; } lds[q * LDSP + r] = v.z;
            if (++r == NCLS) { r = 0; ++q; } lds[q * LDSP + r] = v.w;
        }
    }
    if (t < PPB) {                              // padding = -inf
        lds[t * LDSP + 81] = -INFINITY;
        lds[t * LDSP + 82] = -INFINITY;
        lds[t * LDSP + 83] = -INFINITY;
    }
    __syncthreads();

    // ---- online softmax: thread t -> prior q = t>>2, quarter h = t&3
    const int q = t >> 2, h = t & 3;
    const float4* lp = reinterpret_cast<const float4*>(&lds[q * LDSP + h * 20]);
    float m = -INFINITY, s = 0.0f;
#define ONLINE(v)                                                              \
    do {                                                                       \
        const float m4 = fmaxf(fmaxf((v).x, (v).y), fmaxf((v).z, (v).w));      \
        const float mn = fmaxf(m, m4);                                         \
        s = s * __expf(m - mn) + __expf((v).x - mn) + __expf((v).y - mn)       \
          + __expf((v).z - mn) + __expf((v).w - mn);                           \
        m = mn;                                                                \
    } while (0)
#pragma unroll
    for (int j = 0; j < 5; ++j) { const float4 v = lp[j]; ONLINE(v); }
    if (h == 3)                  { const float4 v = lp[5]; ONLINE(v); }
#undef ONLINE
    // merge (m,s) across the 4 lanes of this prior
#pragma unroll
    for (int off = 1; off <= 2; off <<= 1) {
        const float mo = __shfl_xor(m, off, 64);
        const float so = __shfl_xor(s, off, 64);
        const float mn = fmaxf(m, mo);
        s = s * __expf(m - mn) + so * __expf(mo - mn);
        m = mn;
    }
    const float lse = m + __logf(s);

    // ---- outputs (h==0 lane of each prior)
    float cep = 0.0f, sl = 0.0f;
    if (h == 0) {
        const int p = b * PPB + q;
        const int lab = labels[p];
        const float c0 = lds[q * LDSP];
        unsigned key = 0u;
        if (lab > 0) {
            cep = lse - lds[q * LDSP + lab];    // positive cross-entropy
            const float4 pl = *reinterpret_cast<const float4*>(ploc + (size_t)p * 4);
            const float4 gl = *reinterpret_cast<const float4*>(gloc + (size_t)p * 4);
            float d, a;
            d = pl.x - gl.x; a = fabsf(d); sl += (a < 1.0f) ? 0.5f * d * d : a - 0.5f;
            d = pl.y - gl.y; a = fabsf(d); sl += (a < 1.0f) ? 0.5f * d * d : a - 0.5f;
            d = pl.z - gl.z; a = fabsf(d); sl += (a < 1.0f) ? 0.5f * d * d : a - 0.5f;
            d = pl.w - gl.w; a = fabsf(d); sl += (a < 1.0f) ? 0.5f * d * d : a - 0.5f;
        } else {
            key = keymap(lse - c0);             // bg >= 0 -> key >= 0x80000000
        }
        keysg[p] = key;
    }

    // ---- block reduce partials
#pragma unroll
    for (int off = 32; off > 0; off >>= 1) {
        cep += __shfl_xor(cep, off, 64);
        sl  += __shfl_xor(sl,  off, 64);
    }
    const int wid = t >> 6, lane = t & 63;
    if (lane == 0) { red0[wid] = cep; red1[wid] = sl; }
    __syncthreads();
    if (t == 0) {
        cepart[b] = red0[0] + red0[1] + red0[2] + red0[3];
        slpart[b] = red1[0] + red1[1] + red1[2] + red1[3];
    }
}

// ---------------------------------------------------------------------------
// Kernel 2: one block (1024 thr) per batch row. Keys-only input. Fused
// stage + level-3 histogram with wave-aggregated atomics; exact 4x8-bit
// radix select; selected sum reconstructed from keys. Per-row results to
// rowacc; last block (ticket counter) does deterministic final reduce.
// ---------------------------------------------------------------------------
__global__ __launch_bounds__(1024) void k_row(const unsigned* __restrict__ keysg,
                                              const float* __restrict__ cepart,
                                              const float* __restrict__ slpart,
                                              unsigned* __restrict__ counter,
                                              float* __restrict__ rowobj,
                                              float* __restrict__ rowsl,
                                              float* __restrict__ rownp,
                                              float* __restrict__ out) {
    __shared__ unsigned keys_s[PRI];            // 34928 B
    __shared__ unsigned hist[256];
    __shared__ unsigned ured[16];
    __shared__ float    fred[16], fred2[16];
    __shared__ unsigned sh_prefix, sh_r;
    __shared__ int      sh_flag;

    const int row  = blockIdx.x;
    const int tid  = threadIdx.x;
    const int wid  = tid >> 6;
    const int lane = tid & 63;
    const unsigned* krow = keysg + (size_t)row * PRI;

    if (tid < 256) hist[tid] = 0;
    __syncthreads();

    // ---- stage + count positives + level-3 histogram (wave-aggregated)
    unsigned np = 0;
    for (int jb = 0; jb < PRI; jb += 1024) {
        const int j = jb + tid;
        const bool in = (j < PRI);
        const unsigned key = in ? krow[j] : 0u;
        if (in) keys_s[j] = key;
        np += (in && key == 0u) ? 1u : 0u;
        bool act = in && (key != 0u);
        const unsigned bin = key >> 24;
        while (true) {
            const unsigned long long msk = __ballot(act);
            if (msk == 0ULL) break;
            const int leader = __ffsll((unsigned long long)msk) - 1;
            const unsigned lbin = __shfl(bin, leader, 64);
            const bool same = act && (bin == lbin);
            const unsigned cnt = (unsigned)__popcll(__ballot(same));
            if (lane == leader) atomicAdd(&hist[lbin], cnt);
            act = act && !same;
        }
    }
#pragma unroll
    for (int off = 32; off > 0; off >>= 1) np += __shfl_xor(np, off, 64);
    if (lane == 0) ured[wid] = np;
    __syncthreads();
    unsigned num_pos = 0;
#pragma unroll
    for (int w = 0; w < 16; ++w) num_pos += ured[w];
    const int k = (int)num_pos * NEGPOS;

    // ---- exact radix select (k-th largest negative key)
    unsigned Kstar = 0xFFFFFFFFu;
    int r_eq = 0;
    bool take_all = false;
    if (k > 0) {
        unsigned prefix = 0;
        int r = k, flag = 0;
        for (int level = 3; level >= 0; --level) {
            const int shift = level * 8;
            if (level < 3) {
                if (tid < 256) hist[tid] = 0;
                __syncthreads();
                for (int jb = 0; jb < PRI; jb += 1024) {
                    const int j = jb + tid;
                    const bool in = (j < PRI);
                    const unsigned key = in ? keys_s[j] : 0u;
                    bool act = in && (key != 0u) &&
                               ((key >> (shift + 8)) == (prefix >> (shift + 8)));
                    const unsigned bin = (key >> shift) & 255u;
                    while (true) {
                        const unsigned long long msk = __ballot(act);
                        if (msk == 0ULL) break;
                        const int leader = __ffsll((unsigned long long)msk) - 1;
                        const unsigned lbin = __shfl(bin, leader, 64);
                        const bool same = act && (bin == lbin);
                        const unsigned cnt = (unsigned)__popcll(__ballot(same));
                        if (lane == leader) atomicAdd(&hist[lbin], cnt);
                        act = act && !same;
                    }
                }
                __syncthreads();
            }
            if (wid == 0) {
                const int b0 = lane * 4;
                const unsigned h0 = hist[b0], h1 = hist[b0 + 1];
                const unsigned h2 = hist[b0 + 2], h3 = hist[b0 + 3];
                const unsigned loc = h0 + h1 + h2 + h3;
                unsigned ssum = loc;                  // inclusive suffix scan
#pragma unroll
                for (int o2 = 1; o2 < 64; o2 <<= 1) {
                    const unsigned t2 = __shfl_down(ssum, o2, 64);
                    if (lane + o2 < 64) ssum += t2;
                }
                const unsigned above = ssum - loc;
                const unsigned cum3 = above + h3;
                const unsigned cum2 = cum3 + h2;
                const unsigned cum1 = cum2 + h1;
                const unsigned cum0 = cum1 + h0;
                const unsigned long long msk = __ballot(cum0 >= (unsigned)r);
                if (msk == 0ULL) {
                    if (lane == 0) sh_flag = 1;       // fewer negatives than k
                } else {
                    const int L = 63 - __clzll(msk);
                    if (lane == L) {
                        unsigned selbin, cumsel, hsel;
                        if      (cum3 >= (unsigned)r) { selbin = b0 + 3; cumsel = cum3; hsel = h3; }
                        else if (cum2 >= (unsigned)r) { selbin = b0 + 2; cumsel = cum2; hsel = h2; }
                        else if (cum1 >= (unsigned)r) { selbin = b0 + 1; cumsel = cum1; hsel = h1; }
                        else                          { selbin = b0;     cumsel = cum0; hsel = h0; }
                        sh_prefix = prefix | (selbin << shift);
                        sh_r = (unsigned)r - (cumsel - hsel);
                        sh_flag = 0;
                    }
                }
            }
            __syncthreads();
            flag = sh_flag;
            if (flag) break;
            prefix = sh_prefix;
            r = (int)sh_r;
        }
        take_all = (flag != 0);
        if (!take_all) { Kstar = prefix; r_eq = r; }
    }

    // ---- sum selected negative losses (ce == bg, value recovered from key)
    float obj = 0.0f;
    if (k > 0) {
        for (int j = tid; j < PRI; j += 1024) {
            const unsigned key = keys_s[j];
            if (key != 0u && (take_all || key > Kstar))
                obj += __uint_as_float(key ^ 0x80000000u);
        }
        if (tid == 0 && !take_all)
            obj += (float)r_eq * __uint_as_float(Kstar ^ 0x80000000u);
    }

    // ---- stripe-reduce k_lse partials (positive ce + smooth-L1)
    float sl = 0.0f;
    {
        const int i0 = row * 137 + tid;          // 64*137 = 8768 >= 8732
        if (tid < 137 && i0 < NBLK1) { obj += cepart[i0]; sl = slpart[i0]; }
    }

    // ---- block reduce, write per-row results
#pragma unroll
    for (int off = 32; off > 0; off >>= 1) {
        obj += __shfl_xor(obj, off, 64);
        sl  += __shfl_xor(sl,  off, 64);
    }
    __syncthreads();
    if (lane == 0) { fred[wid] = obj; fred2[wid] = sl; }
    __syncthreads();
    if (tid == 0) {
        float to = 0.0f, ts = 0.0f;
#pragma unroll
        for (int w = 0; w < 16; ++w) { to += fred[w]; ts += fred2[w]; }
        rowobj[row] = to;
        rowsl[row]  = ts;
        rownp[row]  = (float)num_pos;
        __threadfence();                          // release row results
        const unsigned ticket = atomicAdd(counter, 1u);
        sh_flag = (ticket == BATCH - 1) ? -1 : 0; // reuse as last-block flag
    }
    __syncthreads();
    if (sh_flag == -1 && wid == 0) {              // deterministic final reduce
        __threadfence();                          // acquire all rows
        float o = rowobj[lane], s2 = rowsl[lane], n = rownp[lane];
#pragma unroll
        for (int off = 32; off > 0; off >>= 1) {
            o  += __shfl_xor(o,  off, 64);
            s2 += __shfl_xor(s2, off, 64);
            n  += __shfl_xor(n,  off, 64);
        }
        if (lane == 0) {
            const float npos = fmaxf(n, 1.0f);
            out[0] = o / npos;
            out[1] = s2 / npos;
        }
    }
}

extern "C" void kernel_launch(void* const* d_in, const int* in_sizes, int n_in,
                              void* d_out, int out_size, void* d_ws, size_t ws_size,
                              hipStream_t stream) {
    const float* pred_loc  = (const float*)d_in[0];
    const float* pred_conf = (const float*)d_in[1];
    const float* gt_loc    = (const float*)d_in[2];
    const int*   gt_labels = (const int*)d_in[3];
    float* out = (float*)d_out;

    unsigned* counter = (unsigned*)d_ws;                  // 1 u32 (+pad to 16B)
    unsigned* keysg   = (unsigned*)d_ws + 4;              // NTOT u32
    float*    cepart  = (float*)(keysg + NTOT);           // NBLK1 f
    float*    slpart  = cepart + NBLK1;                   // NBLK1 f
    float*    rowobj  = slpart + NBLK1;                   // BATCH f
    float*    rowsl   = rowobj + BATCH;                   // BATCH f
    float*    rownp   = rowsl + BATCH;                    // BATCH f

    hipMemsetAsync(counter, 0, 16, stream);               // zero ticket counter
    k_lse<<<NBLK1, 256, 0, stream>>>(pred_conf, gt_labels, pred_loc, gt_loc,
                                     keysg, cepart, slpart);
    k_row<<<BATCH, 1024, 0, stream>>>(keysg, cepart, slpart, counter,
                                      rowobj, rowsl, rownp, out);
}

// Round 4
// 106.753 us; speedup vs baseline: 1.0354x; 1.0354x over previous
//
#include <hip/hip_runtime.h>
#include <cstdint>
#include <cstddef>

#define BATCH 64
#define PRI   8732
#define NCLS  81
#define NEGPOS 3
#define NTOT  (BATCH * PRI)          // 558848
#define PPB   64                     // priors per k_lse block
#define NBLK1 (NTOT / PPB)           // 8732 exactly
#define WFLOATS (PPB * NCLS)         // 5184 floats per block window
#define WF4   (WFLOATS / 4)          // 1296 float4s per block

__device__ __forceinline__ unsigned keymap(float f) {
    unsigned u = __float_as_uint(f);
    return (u & 0x80000000u) ? ~u : (u | 0x80000000u);
}

// ---------------------------------------------------------------------------
// Kernel 1: 256 threads / 64 priors per block.
// Stage the block's 20736 B contiguously into LDS (coalesced float4 global
// loads, LINEAR ds_write_b128 — no scatter, no address math). Then 4 threads
// per prior: aligned ds_read_b128 of a 24-float window covering a 20/21-float
// quarter (edges masked to -inf), two-phase max+sumexp in registers, 2-shfl
// (m,s) merge. h==0 lane emits keymapped bg key (positives -> 0), positive ce
// and fused smooth-L1 into per-block partials.
// ---------------------------------------------------------------------------
__global__ __launch_bounds__(256) void k_lse(const float* __restrict__ conf,
                                             const int* __restrict__ labels,
                                             const float* __restrict__ ploc,
                                             const float* __restrict__ gloc,
                                             unsigned* __restrict__ keysg,
                                             float* __restrict__ cepart,
                                             float* __restrict__ slpart) {
    __shared__ float lds[WFLOATS + 16];
    __shared__ int   labs[PPB];
    __shared__ float red0[4], red1[4];
    const int t = threadIdx.x;
    const int b = blockIdx.x;

    // ---- linear stage: global float4 i -> LDS float4 i (both coalesced)
    const float4* g4 = reinterpret_cast<const float4*>(conf) + (size_t)b * WF4;
    float4* l4 = reinterpret_cast<float4*>(lds);
#pragma unroll
    for (int j = 0; j < 5; ++j) l4[t + 256 * j] = g4[t + 256 * j];
    if (t < WF4 - 1280) l4[t + 1280] = g4[t + 1280];       // 16 threads
    if (t < PPB) labs[t] = labels[b * PPB + t];
    __syncthreads();

    // ---- softmax: thread t -> prior q = t>>2, quarter h = t&3
    const int q   = t >> 2, h = t & 3;
    const int f0  = q * NCLS + 20 * h;        // quarter start (float index)
    const int len = (h == 3) ? 21 : 20;
    const int a0  = f0 & ~3;                  // aligned window start
    const int o   = f0 & 3;                   // head offset 0..3
    const int ve  = o + len;                  // first-invalid in window, 20..24

    const float4* lp = reinterpret_cast<const float4*>(lds + a0);
    float4 v0 = lp[0], v1 = lp[1], v2 = lp[2], v3 = lp[3], v4 = lp[4], v5 = lp[5];
    // head mask (elements e < o)
    v0.x = (o > 0) ? -INFINITY : v0.x;
    v0.y = (o > 1) ? -INFINITY : v0.y;
    v0.z = (o > 2) ? -INFINITY : v0.z;
    // tail mask in v5 (elements e=20..23 valid iff e < ve)
    v5.x = (ve > 20) ? v5.x : -INFINITY;
    v5.y = (ve > 21) ? v5.y : -INFINITY;
    v5.z = (ve > 22) ? v5.z : -INFINITY;
    v5.w = (ve > 23) ? v5.w : -INFINITY;

    // two-phase: max of 24, then sum of exp
    float m;
    {
        float a = fmaxf(fmaxf(v0.x, v0.y), fmaxf(v0.z, v0.w));
        float c = fmaxf(fmaxf(v1.x, v1.y), fmaxf(v1.z, v1.w));
        float d = fmaxf(fmaxf(v2.x, v2.y), fmaxf(v2.z, v2.w));
        float e = fmaxf(fmaxf(v3.x, v3.y), fmaxf(v3.z, v3.w));
        float f = fmaxf(fmaxf(v4.x, v4.y), fmaxf(v4.z, v4.w));
        float g = fmaxf(fmaxf(v5.x, v5.y), fmaxf(v5.z, v5.w));
        m = fmaxf(fmaxf(fmaxf(a, c), fmaxf(d, e)), fmaxf(f, g));
    }
    float s =
        __expf(v0.x - m) + __expf(v0.y - m) + __expf(v0.z - m) + __expf(v0.w - m) +
        __expf(v1.x - m) + __expf(v1.y - m) + __expf(v1.z - m) + __expf(v1.w - m) +
        __expf(v2.x - m) + __expf(v2.y - m) + __expf(v2.z - m) + __expf(v2.w - m) +
        __expf(v3.x - m) + __expf(v3.y - m) + __expf(v3.z - m) + __expf(v3.w - m) +
        __expf(v4.x - m) + __expf(v4.y - m) + __expf(v4.z - m) + __expf(v4.w - m) +
        __expf(v5.x - m) + __expf(v5.y - m) + __expf(v5.z - m) + __expf(v5.w - m);

    // merge (m,s) across the 4 quarter-lanes of this prior
#pragma unroll
    for (int off = 1; off <= 2; off <<= 1) {
        const float mo = __shfl_xor(m, off, 64);
        const float so = __shfl_xor(s, off, 64);
        const float mn = fmaxf(m, mo);
        s = s * __expf(m - mn) + so * __expf(mo - mn);
        m = mn;
    }
    const float lse = m + __logf(s);

    // ---- outputs (h==0 lane of each prior)
    float cep = 0.0f, sl = 0.0f;
    if (h == 0) {
        const int p   = b * PPB + q;
        const int lab = labs[q];
        const float c0 = lds[q * NCLS];
        unsigned key = 0u;
        if (lab > 0) {
            cep = lse - lds[q * NCLS + lab];            // positive cross-entropy
            const float4 pl = *reinterpret_cast<const float4*>(ploc + (size_t)p * 4);
            const float4 gl = *reinterpret_cast<const float4*>(gloc + (size_t)p * 4);
            float d, a;
            d = pl.x - gl.x; a = fabsf(d); sl += (a < 1.0f) ? 0.5f * d * d : a - 0.5f;
            d = pl.y - gl.y; a = fabsf(d); sl += (a < 1.0f) ? 0.5f * d * d : a - 0.5f;
            d = pl.z - gl.z; a = fabsf(d); sl += (a < 1.0f) ? 0.5f * d * d : a - 0.5f;
            d = pl.w - gl.w; a = fabsf(d); sl += (a < 1.0f) ? 0.5f * d * d : a - 0.5f;
        } else {
            key = keymap(lse - c0);        // bg >= 0 -> key >= 0x80000000 != 0
        }
        keysg[p] = key;
    }

    // ---- block reduce partials
#pragma unroll
    for (int off = 32; off > 0; off >>= 1) {
        cep += __shfl_xor(cep, off, 64);
        sl  += __shfl_xor(sl,  off, 64);
    }
    const int wid = t >> 6, lane = t & 63;
    if (lane == 0) { red0[wid] = cep; red1[wid] = sl; }
    __syncthreads();
    if (t == 0) {
        cepart[b] = red0[0] + red0[1] + red0[2] + red0[3];
        slpart[b] = red1[0] + red1[1] + red1[2] + red1[3];
    }
}

// ---------------------------------------------------------------------------
// Kernel 2: one block (1024 thr) per batch row. Keys-only input. Fused
// stage + level-3 histogram with wave-aggregated atomics; exact 4x8-bit
// radix select; selected sum reconstructed from keys. Per-row results to
// rowacc; last block (ticket counter) does deterministic final reduce.
// ---------------------------------------------------------------------------
__global__ __launch_bounds__(1024) void k_row(const unsigned* __restrict__ keysg,
                                              const float* __restrict__ cepart,
                                              const float* __restrict__ slpart,
                                              unsigned* __restrict__ counter,
                                              float* __restrict__ rowobj,
                                              float* __restrict__ rowsl,
                                              float* __restrict__ rownp,
                                              float* __restrict__ out) {
    __shared__ unsigned keys_s[PRI];            // 34928 B
    __shared__ unsigned hist[256];
    __shared__ unsigned ured[16];
    __shared__ float    fred[16], fred2[16];
    __shared__ unsigned sh_prefix, sh_r;
    __shared__ int      sh_flag;

    const int row  = blockIdx.x;
    const int tid  = threadIdx.x;
    const int wid  = tid >> 6;
    const int lane = tid & 63;
    const unsigned* krow = keysg + (size_t)row * PRI;

    if (tid < 256) hist[tid] = 0;
    __syncthreads();

    // ---- stage + count positives + level-3 histogram (wave-aggregated)
    unsigned np = 0;
    for (int jb = 0; jb < PRI; jb += 1024) {
        const int j = jb + tid;
        const bool in = (j < PRI);
        const unsigned key = in ? krow[j] : 0u;
        if (in) keys_s[j] = key;
        np += (in && key == 0u) ? 1u : 0u;
        bool act = in && (key != 0u);
        const unsigned bin = key >> 24;
        while (true) {
            const unsigned long long msk = __ballot(act);
            if (msk == 0ULL) break;
            const int leader = __ffsll((unsigned long long)msk) - 1;
            const unsigned lbin = __shfl(bin, leader, 64);
            const bool same = act && (bin == lbin);
            const unsigned cnt = (unsigned)__popcll(__ballot(same));
            if (lane == leader) atomicAdd(&hist[lbin], cnt);
            act = act && !same;
        }
    }
#pragma unroll
    for (int off = 32; off > 0; off >>= 1) np += __shfl_xor(np, off, 64);
    if (lane == 0) ured[wid] = np;
    __syncthreads();
    unsigned num_pos = 0;
#pragma unroll
    for (int w = 0; w < 16; ++w) num_pos += ured[w];
    const int k = (int)num_pos * NEGPOS;

    // ---- exact radix select (k-th largest negative key)
    unsigned Kstar = 0xFFFFFFFFu;
    int r_eq = 0;
    bool take_all = false;
    if (k > 0) {
        unsigned prefix = 0;
        int r = k, flag = 0;
        for (int level = 3; level >= 0; --level) {
            const int shift = level * 8;
            if (level < 3) {
                if (tid < 256) hist[tid] = 0;
                __syncthreads();
                for (int jb = 0; jb < PRI; jb += 1024) {
                    const int j = jb + tid;
                    const bool in = (j < PRI);
                    const unsigned key = in ? keys_s[j] : 0u;
                    bool act = in && (key != 0u) &&
                               ((key >> (shift + 8)) == (prefix >> (shift + 8)));
                    const unsigned bin = (key >> shift) & 255u;
                    while (true) {
                        const unsigned long long msk = __ballot(act);
                        if (msk == 0ULL) break;
                        const int leader = __ffsll((unsigned long long)msk) - 1;
                        const unsigned lbin = __shfl(bin, leader, 64);
                        const bool same = act && (bin == lbin);
                        const unsigned cnt = (unsigned)__popcll(__ballot(same));
                        if (lane == leader) atomicAdd(&hist[lbin], cnt);
                        act = act && !same;
                    }
                }
                __syncthreads();
            }
            if (wid == 0) {
                const int b0 = lane * 4;
                const unsigned h0 = hist[b0], h1 = hist[b0 + 1];
                const unsigned h2 = hist[b0 + 2], h3 = hist[b0 + 3];
                const unsigned loc = h0 + h1 + h2 + h3;
                unsigned ssum = loc;                  // inclusive suffix scan
#pragma unroll
                for (int o2 = 1; o2 < 64; o2 <<= 1) {
                    const unsigned t2 = __shfl_down(ssum, o2, 64);
                    if (lane + o2 < 64) ssum += t2;
                }
                const unsigned above = ssum - loc;
                const unsigned cum3 = above + h3;
                const unsigned cum2 = cum3 + h2;
                const unsigned cum1 = cum2 + h1;
                const unsigned cum0 = cum1 + h0;
                const unsigned long long msk = __ballot(cum0 >= (unsigned)r);
                if (msk == 0ULL) {
                    if (lane == 0) sh_flag = 1;       // fewer negatives than k
                } else {
                    const int L = 63 - __clzll(msk);
                    if (lane == L) {
                        unsigned selbin, cumsel, hsel;
                        if      (cum3 >= (unsigned)r) { selbin = b0 + 3; cumsel = cum3; hsel = h3; }
                        else if (cum2 >= (unsigned)r) { selbin = b0 + 2; cumsel = cum2; hsel = h2; }
                        else if (cum1 >= (unsigned)r) { selbin = b0 + 1; cumsel = cum1; hsel = h1; }
                        else                          { selbin = b0;     cumsel = cum0; hsel = h0; }
                        sh_prefix = prefix | (selbin << shift);
                        sh_r = (unsigned)r - (cumsel - hsel);
                        sh_flag = 0;
                    }
                }
            }
            __syncthreads();
            flag = sh_flag;
            if (flag) break;
            prefix = sh_prefix;
            r = (int)sh_r;
        }
        take_all = (flag != 0);
        if (!take_all) { Kstar = prefix; r_eq = r; }
    }

    // ---- sum selected negative losses (ce == bg, value recovered from key)
    float obj = 0.0f;
    if (k > 0) {
        for (int j = tid; j < PRI; j += 1024) {
            const unsigned key = keys_s[j];
            if (key != 0u && (take_all || key > Kstar))
                obj += __uint_as_float(key ^ 0x80000000u);
        }
        if (tid == 0 && !take_all)
            obj += (float)r_eq * __uint_as_float(Kstar ^ 0x80000000u);
    }

    // ---- stripe-reduce k_lse partials (positive ce + smooth-L1)
    float sl = 0.0f;
    {
        const int i0 = row * 137 + tid;          // 64*137 = 8768 >= 8732
        if (tid < 137 && i0 < NBLK1) { obj += cepart[i0]; sl = slpart[i0]; }
    }

    // ---- block reduce, write per-row results
#pragma unroll
    for (int off = 32; off > 0; off >>= 1) {
        obj += __shfl_xor(obj, off, 64);
        sl  += __shfl_xor(sl,  off, 64);
    }
    __syncthreads();
    if (lane == 0) { fred[wid] = obj; fred2[wid] = sl; }
    __syncthreads();
    if (tid == 0) {
        float to = 0.0f, ts = 0.0f;
#pragma unroll
        for (int w = 0; w < 16; ++w) { to += fred[w]; ts += fred2[w]; }
        rowobj[row] = to;
        rowsl[row]  = ts;
        rownp[row]  = (float)num_pos;
        __threadfence();                          // release row results
        const unsigned ticket = atomicAdd(counter, 1u);
        sh_flag = (ticket == BATCH - 1) ? -1 : 0; // reuse as last-block flag
    }
    __syncthreads();
    if (sh_flag == -1 && wid == 0) {              // deterministic final reduce
        __threadfence();                          // acquire all rows
        float o = rowobj[lane], s2 = rowsl[lane], n = rownp[lane];
#pragma unroll
        for (int off = 32; off > 0; off >>= 1) {
            o  += __shfl_xor(o,  off, 64);
            s2 += __shfl_xor(s2, off, 64);
            n  += __shfl_xor(n,  off, 64);
        }
        if (lane == 0) {
            const float npos = fmaxf(n, 1.0f);
            out[0] = o / npos;
            out[1] = s2 / npos;
        }
    }
}

extern "C" void kernel_launch(void* const* d_in, const int* in_sizes, int n_in,
                              void* d_out, int out_size, void* d_ws, size_t ws_size,
                              hipStream_t stream) {
    const float* pred_loc  = (const float*)d_in[0];
    const float* pred_conf = (const float*)d_in[1];
    const float* gt_loc    = (const float*)d_in[2];
    const int*   gt_labels = (const int*)d_in[3];
    float* out = (float*)d_out;

    unsigned* counter = (unsigned*)d_ws;                  // 16 B
    unsigned* keysg   = (unsigned*)d_ws + 4;              // NTOT u32
    float*    cepart  = (float*)(keysg + NTOT);           // NBLK1 f
    float*    slpart  = cepart + NBLK1;                   // NBLK1 f
    float*    rowobj  = slpart + NBLK1;                   // BATCH f
    float*    rowsl   = rowobj + BATCH;                   // BATCH f
    float*    rownp   = rowsl + BATCH;                    // BATCH f

    hipMemsetAsync(counter, 0, 16, stream);               // zero ticket counter
    k_lse<<<NBLK1, 256, 0, stream>>>(pred_conf, gt_labels, pred_loc, gt_loc,
                                     keysg, cepart, slpart);
    k_row<<<BATCH, 1024, 0, stream>>>(keysg, cepart, slpart, counter,
                                      rowobj, rowsl, rownp, out);
}

// Round 5
// 64.789 us; speedup vs baseline: 1.7060x; 1.6477x over previous
//
#include <hip/hip_runtime.h>
#include <cstdint>
#include <cstddef>

#define BATCH 64
#define PRI   8732
#define NCLS  81
#define NEGPOS 3
#define NTOT  (BATCH * PRI)          // 558848
#define PPB   64                     // priors per k_lse block
#define NBLK1 (NTOT / PPB)           // 8732 exactly
#define WFLOATS (PPB * NCLS)         // 5184 floats per block window
#define WF4   (WFLOATS / 4)          // 1296 float4s per block

__device__ __forceinline__ unsigned keymap(float f) {
    unsigned u = __float_as_uint(f);
    return (u & 0x80000000u) ? ~u : (u | 0x80000000u);
}

// ---------------------------------------------------------------------------
// Kernel 1 (unchanged from R4): 256 threads / 64 priors per block.
// Linear coalesced global->LDS stage, 4 threads/prior aligned ds_read_b128
// with -inf edge masks, 2-shfl (m,s) merge. Emits keymapped bg keys
// (positives -> 0), per-block positive-ce and smooth-L1 partials.
// ---------------------------------------------------------------------------
__global__ __launch_bounds__(256) void k_lse(const float* __restrict__ conf,
                                             const int* __restrict__ labels,
                                             const float* __restrict__ ploc,
                                             const float* __restrict__ gloc,
                                             unsigned* __restrict__ keysg,
                                             float* __restrict__ cepart,
                                             float* __restrict__ slpart) {
    __shared__ float lds[WFLOATS + 16];
    __shared__ int   labs[PPB];
    __shared__ float red0[4], red1[4];
    const int t = threadIdx.x;
    const int b = blockIdx.x;

    // ---- linear stage: global float4 i -> LDS float4 i (both coalesced)
    const float4* g4 = reinterpret_cast<const float4*>(conf) + (size_t)b * WF4;
    float4* l4 = reinterpret_cast<float4*>(lds);
#pragma unroll
    for (int j = 0; j < 5; ++j) l4[t + 256 * j] = g4[t + 256 * j];
    if (t < WF4 - 1280) l4[t + 1280] = g4[t + 1280];       // 16 threads
    if (t < PPB) labs[t] = labels[b * PPB + t];
    __syncthreads();

    // ---- softmax: thread t -> prior q = t>>2, quarter h = t&3
    const int q   = t >> 2, h = t & 3;
    const int f0  = q * NCLS + 20 * h;        // quarter start (float index)
    const int len = (h == 3) ? 21 : 20;
    const int a0  = f0 & ~3;                  // aligned window start
    const int o   = f0 & 3;                   // head offset 0..3
    const int ve  = o + len;                  // first-invalid in window, 20..24

    const float4* lp = reinterpret_cast<const float4*>(lds + a0);
    float4 v0 = lp[0], v1 = lp[1], v2 = lp[2], v3 = lp[3], v4 = lp[4], v5 = lp[5];
    // head mask (elements e < o)
    v0.x = (o > 0) ? -INFINITY : v0.x;
    v0.y = (o > 1) ? -INFINITY : v0.y;
    v0.z = (o > 2) ? -INFINITY : v0.z;
    // tail mask in v5 (elements e=20..23 valid iff e < ve)
    v5.x = (ve > 20) ? v5.x : -INFINITY;
    v5.y = (ve > 21) ? v5.y : -INFINITY;
    v5.z = (ve > 22) ? v5.z : -INFINITY;
    v5.w = (ve > 23) ? v5.w : -INFINITY;

    float m;
    {
        float a = fmaxf(fmaxf(v0.x, v0.y), fmaxf(v0.z, v0.w));
        float c = fmaxf(fmaxf(v1.x, v1.y), fmaxf(v1.z, v1.w));
        float d = fmaxf(fmaxf(v2.x, v2.y), fmaxf(v2.z, v2.w));
        float e = fmaxf(fmaxf(v3.x, v3.y), fmaxf(v3.z, v3.w));
        float f = fmaxf(fmaxf(v4.x, v4.y), fmaxf(v4.z, v4.w));
        float g = fmaxf(fmaxf(v5.x, v5.y), fmaxf(v5.z, v5.w));
        m = fmaxf(fmaxf(fmaxf(a, c), fmaxf(d, e)), fmaxf(f, g));
    }
    float s =
        __expf(v0.x - m) + __expf(v0.y - m) + __expf(v0.z - m) + __expf(v0.w - m) +
        __expf(v1.x - m) + __expf(v1.y - m) + __expf(v1.z - m) + __expf(v1.w - m) +
        __expf(v2.x - m) + __expf(v2.y - m) + __expf(v2.z - m) + __expf(v2.w - m) +
        __expf(v3.x - m) + __expf(v3.y - m) + __expf(v3.z - m) + __expf(v3.w - m) +
        __expf(v4.x - m) + __expf(v4.y - m) + __expf(v4.z - m) + __expf(v4.w - m) +
        __expf(v5.x - m) + __expf(v5.y - m) + __expf(v5.z - m) + __expf(v5.w - m);

#pragma unroll
    for (int off = 1; off <= 2; off <<= 1) {
        const float mo = __shfl_xor(m, off, 64);
        const float so = __shfl_xor(s, off, 64);
        const float mn = fmaxf(m, mo);
        s = s * __expf(m - mn) + so * __expf(mo - mn);
        m = mn;
    }
    const float lse = m + __logf(s);

    // ---- outputs (h==0 lane of each prior)
    float cep = 0.0f, sl = 0.0f;
    if (h == 0) {
        const int p   = b * PPB + q;
        const int lab = labs[q];
        const float c0 = lds[q * NCLS];
        unsigned key = 0u;
        if (lab > 0) {
            cep = lse - lds[q * NCLS + lab];            // positive cross-entropy
            const float4 pl = *reinterpret_cast<const float4*>(ploc + (size_t)p * 4);
            const float4 gl = *reinterpret_cast<const float4*>(gloc + (size_t)p * 4);
            float d, a;
            d = pl.x - gl.x; a = fabsf(d); sl += (a < 1.0f) ? 0.5f * d * d : a - 0.5f;
            d = pl.y - gl.y; a = fabsf(d); sl += (a < 1.0f) ? 0.5f * d * d : a - 0.5f;
            d = pl.z - gl.z; a = fabsf(d); sl += (a < 1.0f) ? 0.5f * d * d : a - 0.5f;
            d = pl.w - gl.w; a = fabsf(d); sl += (a < 1.0f) ? 0.5f * d * d : a - 0.5f;
        } else {
            key = keymap(lse - c0);        // bg >= 0 -> key >= 0x80000000 != 0
        }
        keysg[p] = key;
    }

    // ---- block reduce partials
#pragma unroll
    for (int off = 32; off > 0; off >>= 1) {
        cep += __shfl_xor(cep, off, 64);
        sl  += __shfl_xor(sl,  off, 64);
    }
    const int wid = t >> 6, lane = t & 63;
    if (lane == 0) { red0[wid] = cep; red1[wid] = sl; }
    __syncthreads();
    if (t == 0) {
        cepart[b] = red0[0] + red0[1] + red0[2] + red0[3];
        slpart[b] = red1[0] + red1[1] + red1[2] + red1[3];
    }
}

// ---------------------------------------------------------------------------
// Kernel 2 (R2-style): one block (1024 thr) per batch row, keys-only input.
// Plain wave-private LDS histogram atomics (NO ballot aggregation), exact
// 4x8-bit radix select, selected sum reconstructed from keys. No fences,
// no ticket counter — per-row results only.
// ---------------------------------------------------------------------------
__global__ __launch_bounds__(1024) void k_row(const unsigned* __restrict__ keysg,
                                              float* __restrict__ rowobj,
                                              float* __restrict__ rownp) {
    __shared__ unsigned keys_s[PRI];            // 34928 B
    __shared__ unsigned hist[16][257];          // wave-private, padded: 16448 B
    __shared__ unsigned ured[16];
    __shared__ float    fred[16];
    __shared__ unsigned sh_prefix, sh_r;
    __shared__ int      sh_flag;

    const int row  = blockIdx.x;
    const int tid  = threadIdx.x;
    const int wid  = tid >> 6;
    const int lane = tid & 63;
    const unsigned* krow = keysg + (size_t)row * PRI;

    // ---- stage keys + count positives (key==0 sentinel)
    unsigned np = 0;
    for (int j = tid; j < PRI; j += 1024) {
        const unsigned key = krow[j];
        keys_s[j] = key;
        np += (key == 0u) ? 1u : 0u;
    }
#pragma unroll
    for (int off = 32; off > 0; off >>= 1) np += __shfl_xor(np, off, 64);
    if (lane == 0) ured[wid] = np;
    __syncthreads();
    unsigned num_pos = 0;
#pragma unroll
    for (int w = 0; w < 16; ++w) num_pos += ured[w];
    const int k = (int)num_pos * NEGPOS;

    // ---- exact radix select (k-th largest negative key)
    unsigned Kstar = 0xFFFFFFFFu;
    int r_eq = 0;
    bool take_all = false;
    if (k > 0) {
        unsigned prefix = 0;
        int r = k, flag = 0;
        unsigned* hist_flat = &hist[0][0];
        for (int level = 3; level >= 0; --level) {
            const int shift = level * 8;
            for (int i = tid; i < 16 * 257; i += 1024) hist_flat[i] = 0;
            __syncthreads();
            for (int j = tid; j < PRI; j += 1024) {
                const unsigned key = keys_s[j];
                if (key == 0u) continue;
                if (level < 3 && (key >> (shift + 8)) != (prefix >> (shift + 8))) continue;
                atomicAdd(&hist[wid][(key >> shift) & 255u], 1u);
            }
            __syncthreads();
            if (wid == 0) {
                const int b0 = lane * 4;
                unsigned h0 = 0, h1 = 0, h2 = 0, h3 = 0;
#pragma unroll
                for (int w = 0; w < 16; ++w) {
                    h0 += hist[w][b0]; h1 += hist[w][b0 + 1];
                    h2 += hist[w][b0 + 2]; h3 += hist[w][b0 + 3];
                }
                const unsigned loc = h0 + h1 + h2 + h3;
                unsigned ssum = loc;                  // inclusive suffix scan
#pragma unroll
                for (int o2 = 1; o2 < 64; o2 <<= 1) {
                    const unsigned t2 = __shfl_down(ssum, o2, 64);
                    if (lane + o2 < 64) ssum += t2;
                }
                const unsigned above = ssum - loc;
                const unsigned cum3 = above + h3;
                const unsigned cum2 = cum3 + h2;
                const unsigned cum1 = cum2 + h1;
                const unsigned cum0 = cum1 + h0;
                const unsigned long long msk = __ballot(cum0 >= (unsigned)r);
                if (msk == 0ULL) {
                    if (lane == 0) sh_flag = 1;       // fewer negatives than k
                } else {
                    const int L = 63 - __clzll(msk);
                    if (lane == L) {
                        unsigned selbin, cumsel, hsel;
                        if      (cum3 >= (unsigned)r) { selbin = b0 + 3; cumsel = cum3; hsel = h3; }
                        else if (cum2 >= (unsigned)r) { selbin = b0 + 2; cumsel = cum2; hsel = h2; }
                        else if (cum1 >= (unsigned)r) { selbin = b0 + 1; cumsel = cum1; hsel = h1; }
                        else                          { selbin = b0;     cumsel = cum0; hsel = h0; }
                        sh_prefix = prefix | (selbin << shift);
                        sh_r = (unsigned)r - (cumsel - hsel);
                        sh_flag = 0;
                    }
                }
            }
            __syncthreads();
            flag = sh_flag;
            if (flag) break;
            prefix = sh_prefix;
            r = (int)sh_r;
        }
        take_all = (flag != 0);
        if (!take_all) { Kstar = prefix; r_eq = r; }
    }

    // ---- sum selected negative losses (ce == bg, value recovered from key)
    float obj = 0.0f;
    if (k > 0) {
        for (int j = tid; j < PRI; j += 1024) {
            const unsigned key = keys_s[j];
            if (key != 0u && (take_all || key > Kstar))
                obj += __uint_as_float(key ^ 0x80000000u);
        }
        if (tid == 0 && !take_all)
            obj += (float)r_eq * __uint_as_float(Kstar ^ 0x80000000u);
    }

    // ---- block reduce, write per-row results
#pragma unroll
    for (int off = 32; off > 0; off >>= 1) obj += __shfl_xor(obj, off, 64);
    __syncthreads();
    if (lane == 0) fred[wid] = obj;
    __syncthreads();
    if (tid == 0) {
        float to = 0.0f;
#pragma unroll
        for (int w = 0; w < 16; ++w) to += fred[w];
        rowobj[row] = to;
        rownp[row]  = (float)num_pos;
    }
}

// ---------------------------------------------------------------------------
// Kernel 3: final reduction -> 2 scalars (reduces k_lse partials too)
// ---------------------------------------------------------------------------
__global__ __launch_bounds__(256) void k_final(const float* __restrict__ cepart,
                                               const float* __restrict__ slpart,
                                               const float* __restrict__ rowobj,
                                               const float* __restrict__ rownp,
                                               float* __restrict__ out) {
    const int tid = threadIdx.x;
    float ce = 0.0f, sl = 0.0f;
    for (int i = tid; i < NBLK1; i += 256) { ce += cepart[i]; sl += slpart[i]; }
    float ro = 0.0f, np = 0.0f;
    if (tid < BATCH) { ro = rowobj[tid]; np = rownp[tid]; }
#pragma unroll
    for (int off = 32; off > 0; off >>= 1) {
        ce += __shfl_xor(ce, off, 64);
        sl += __shfl_xor(sl, off, 64);
        ro += __shfl_xor(ro, off, 64);
        np += __shfl_xor(np, off, 64);
    }
    __shared__ float r0[4], r1[4], r2[4], r3[4];
    const int wid = tid >> 6, lane = tid & 63;
    if (lane == 0) { r0[wid] = ce; r1[wid] = sl; r2[wid] = ro; r3[wid] = np; }
    __syncthreads();
    if (tid == 0) {
        const float tce = r0[0] + r0[1] + r0[2] + r0[3];
        const float tsl = r1[0] + r1[1] + r1[2] + r1[3];
        const float tro = r2[0] + r2[1] + r2[2] + r2[3];
        const float tnp = r3[0] + r3[1] + r3[2] + r3[3];
        const float npos = fmaxf(tnp, 1.0f);
        out[0] = (tce + tro) / npos;
        out[1] = tsl / npos;
    }
}

extern "C" void kernel_launch(void* const* d_in, const int* in_sizes, int n_in,
                              void* d_out, int out_size, void* d_ws, size_t ws_size,
                              hipStream_t stream) {
    const float* pred_loc  = (const float*)d_in[0];
    const float* pred_conf = (const float*)d_in[1];
    const float* gt_loc    = (const float*)d_in[2];
    const int*   gt_labels = (const int*)d_in[3];
    float* out = (float*)d_out;

    unsigned* keysg   = (unsigned*)d_ws;                  // NTOT u32
    float*    cepart  = (float*)(keysg + NTOT);           // NBLK1 f
    float*    slpart  = cepart + NBLK1;                   // NBLK1 f
    float*    rowobj  = slpart + NBLK1;                   // BATCH f
    float*    rownp   = rowobj + BATCH;                   // BATCH f

    k_lse<<<NBLK1, 256, 0, stream>>>(pred_conf, gt_labels, pred_loc, gt_loc,
                                     keysg, cepart, slpart);
    k_row<<<BATCH, 1024, 0, stream>>>(keysg, rowobj, rownp);
    k_final<<<1, 256, 0, stream>>>(cepart, slpart, rowobj, rownp, out);
}

// Round 6
// 57.292 us; speedup vs baseline: 1.9292x; 1.1309x over previous
//
#include <hip/hip_runtime.h>
#include <cstdint>
#include <cstddef>

#define BATCH 64
#define PRI   8732
#define NCLS  81
#define NEGPOS 3
#define NTOT  (BATCH * PRI)          // 558848
#define PPB   64                     // priors per window
#define NWIN  (NTOT / PPB)           // 8732 windows
#define WFLOATS (PPB * NCLS)         // 5184 floats per window
#define WF4   (WFLOATS / 4)          // 1296 float4s per window
#define NPERS 768                    // persistent k_lse blocks (3/CU, LDS-lim)

__device__ __forceinline__ unsigned keymap(float f) {
    unsigned u = __float_as_uint(f);
    return (u & 0x80000000u) ? ~u : (u | 0x80000000u);
}

// async global->LDS, 16 B per lane (direct-to-LDS DMA, no VGPR round-trip)
__device__ __forceinline__ void gl_lds16(const float4* g, float4* l) {
    __builtin_amdgcn_global_load_lds(
        (const __attribute__((address_space(1))) void*)(const void*)g,
        (__attribute__((address_space(3))) void*)(void*)l, 16, 0, 0);
}

// ---------------------------------------------------------------------------
// Kernel 1: 768 persistent blocks x 256 threads. Each block owns windows
// w = bid + i*768 (64 priors each). Double-buffered LDS: issue next window's
// global_load_lds DMA, then compute current window's softmax from LDS
// (4 threads/prior, aligned ds_read_b128, -inf edge masks, 2-shfl merge).
// __syncthreads() at iteration end drains vmcnt -> next buffer ready.
// Per-block accumulated positive-ce / smooth-L1 partials (768 entries).
// ---------------------------------------------------------------------------
__global__ __launch_bounds__(256) void k_lse(const float* __restrict__ conf,
                                             const int* __restrict__ labels,
                                             const float* __restrict__ ploc,
                                             const float* __restrict__ gloc,
                                             unsigned* __restrict__ keysg,
                                             float* __restrict__ cepart,
                                             float* __restrict__ slpart) {
    __shared__ float lds[2][WFLOATS];       // 41472 B
    __shared__ int   labs[2][PPB];
    __shared__ float red0[4], red1[4];
    const int t = threadIdx.x;
    const int bid = blockIdx.x;

    float ceacc = 0.0f, slacc = 0.0f;

    auto stage = [&](int buf, int w) {
        const float4* g4 = reinterpret_cast<const float4*>(conf) + (size_t)w * WF4;
        float4* l4 = reinterpret_cast<float4*>(&lds[buf][0]);
#pragma unroll
        for (int j = 0; j < 5; ++j) gl_lds16(&g4[t + 256 * j], &l4[t + 256 * j]);
        if (t < WF4 - 1280) gl_lds16(&g4[t + 1280], &l4[t + 1280]);
        if (t < PPB) labs[buf][t] = labels[w * PPB + t];
    };

    stage(0, bid);
    __syncthreads();                         // drain DMA for first window

    int cur = 0;
    for (int i = 0; ; ++i) {
        const int w  = bid + i * NPERS;
        const int wn = w + NPERS;
        const bool more = (wn < NWIN);
        if (more) stage(cur ^ 1, wn);        // DMA next window under compute

        // ---- compute window w from lds[cur]
        const float* ldsw = &lds[cur][0];
        const int q   = t >> 2, h = t & 3;
        const int f0  = q * NCLS + 20 * h;
        const int len = (h == 3) ? 21 : 20;
        const int a0  = f0 & ~3;
        const int o   = f0 & 3;
        const int ve  = o + len;

        const float4* lp = reinterpret_cast<const float4*>(ldsw + a0);
        float4 v0 = lp[0], v1 = lp[1], v2 = lp[2], v3 = lp[3], v4 = lp[4], v5 = lp[5];
        v0.x = (o > 0) ? -INFINITY : v0.x;
        v0.y = (o > 1) ? -INFINITY : v0.y;
        v0.z = (o > 2) ? -INFINITY : v0.z;
        v5.x = (ve > 20) ? v5.x : -INFINITY;
        v5.y = (ve > 21) ? v5.y : -INFINITY;
        v5.z = (ve > 22) ? v5.z : -INFINITY;
        v5.w = (ve > 23) ? v5.w : -INFINITY;

        float m;
        {
            float a = fmaxf(fmaxf(v0.x, v0.y), fmaxf(v0.z, v0.w));
            float c = fmaxf(fmaxf(v1.x, v1.y), fmaxf(v1.z, v1.w));
            float d = fmaxf(fmaxf(v2.x, v2.y), fmaxf(v2.z, v2.w));
            float e = fmaxf(fmaxf(v3.x, v3.y), fmaxf(v3.z, v3.w));
            float f = fmaxf(fmaxf(v4.x, v4.y), fmaxf(v4.z, v4.w));
            float g = fmaxf(fmaxf(v5.x, v5.y), fmaxf(v5.z, v5.w));
            m = fmaxf(fmaxf(fmaxf(a, c), fmaxf(d, e)), fmaxf(f, g));
        }
        float s =
            __expf(v0.x - m) + __expf(v0.y - m) + __expf(v0.z - m) + __expf(v0.w - m) +
            __expf(v1.x - m) + __expf(v1.y - m) + __expf(v1.z - m) + __expf(v1.w - m) +
            __expf(v2.x - m) + __expf(v2.y - m) + __expf(v2.z - m) + __expf(v2.w - m) +
            __expf(v3.x - m) + __expf(v3.y - m) + __expf(v3.z - m) + __expf(v3.w - m) +
            __expf(v4.x - m) + __expf(v4.y - m) + __expf(v4.z - m) + __expf(v4.w - m) +
            __expf(v5.x - m) + __expf(v5.y - m) + __expf(v5.z - m) + __expf(v5.w - m);

#pragma unroll
        for (int off = 1; off <= 2; off <<= 1) {
            const float mo = __shfl_xor(m, off, 64);
            const float so = __shfl_xor(s, off, 64);
            const float mn = fmaxf(m, mo);
            s = s * __expf(m - mn) + so * __expf(mo - mn);
            m = mn;
        }
        const float lse = m + __logf(s);

        if (h == 0) {
            const int p   = w * PPB + q;
            const int lab = labs[cur][q];
            const float c0 = ldsw[q * NCLS];
            unsigned key = 0u;
            if (lab > 0) {
                ceacc += lse - ldsw[q * NCLS + lab];
                const float4 pl = *reinterpret_cast<const float4*>(ploc + (size_t)p * 4);
                const float4 gl = *reinterpret_cast<const float4*>(gloc + (size_t)p * 4);
                float d, a;
                d = pl.x - gl.x; a = fabsf(d); slacc += (a < 1.0f) ? 0.5f * d * d : a - 0.5f;
                d = pl.y - gl.y; a = fabsf(d); slacc += (a < 1.0f) ? 0.5f * d * d : a - 0.5f;
                d = pl.z - gl.z; a = fabsf(d); slacc += (a < 1.0f) ? 0.5f * d * d : a - 0.5f;
                d = pl.w - gl.w; a = fabsf(d); slacc += (a < 1.0f) ? 0.5f * d * d : a - 0.5f;
            } else {
                key = keymap(lse - c0);       // bg >= 0 -> key >= 0x80000000
            }
            keysg[p] = key;
        }

        if (!more) break;
        __syncthreads();                      // waits DMA(wn) + readers of cur
        cur ^= 1;
    }

    // ---- block reduce accumulated partials
#pragma unroll
    for (int off = 32; off > 0; off >>= 1) {
        ceacc += __shfl_xor(ceacc, off, 64);
        slacc += __shfl_xor(slacc, off, 64);
    }
    const int wid = t >> 6, lane = t & 63;
    __syncthreads();
    if (lane == 0) { red0[wid] = ceacc; red1[wid] = slacc; }
    __syncthreads();
    if (t == 0) {
        cepart[bid] = red0[0] + red0[1] + red0[2] + red0[3];
        slpart[bid] = red1[0] + red1[1] + red1[2] + red1[3];
    }
}

// ---------------------------------------------------------------------------
// Kernel 2 (bit-identical to R5): one block (1024 thr) per batch row,
// keys-only input, wave-private LDS histograms, exact 4x8-bit radix select,
// selected sum reconstructed from keys.
// ---------------------------------------------------------------------------
__global__ __launch_bounds__(1024) void k_row(const unsigned* __restrict__ keysg,
                                              float* __restrict__ rowobj,
                                              float* __restrict__ rownp) {
    __shared__ unsigned keys_s[PRI];            // 34928 B
    __shared__ unsigned hist[16][257];          // wave-private, padded
    __shared__ unsigned ured[16];
    __shared__ float    fred[16];
    __shared__ unsigned sh_prefix, sh_r;
    __shared__ int      sh_flag;

    const int row  = blockIdx.x;
    const int tid  = threadIdx.x;
    const int wid  = tid >> 6;
    const int lane = tid & 63;
    const unsigned* krow = keysg + (size_t)row * PRI;

    unsigned np = 0;
    for (int j = tid; j < PRI; j += 1024) {
        const unsigned key = krow[j];
        keys_s[j] = key;
        np += (key == 0u) ? 1u : 0u;
    }
#pragma unroll
    for (int off = 32; off > 0; off >>= 1) np += __shfl_xor(np, off, 64);
    if (lane == 0) ured[wid] = np;
    __syncthreads();
    unsigned num_pos = 0;
#pragma unroll
    for (int w = 0; w < 16; ++w) num_pos += ured[w];
    const int k = (int)num_pos * NEGPOS;

    unsigned Kstar = 0xFFFFFFFFu;
    int r_eq = 0;
    bool take_all = false;
    if (k > 0) {
        unsigned prefix = 0;
        int r = k, flag = 0;
        unsigned* hist_flat = &hist[0][0];
        for (int level = 3; level >= 0; --level) {
            const int shift = level * 8;
            for (int i = tid; i < 16 * 257; i += 1024) hist_flat[i] = 0;
            __syncthreads();
            for (int j = tid; j < PRI; j += 1024) {
                const unsigned key = keys_s[j];
                if (key == 0u) continue;
                if (level < 3 && (key >> (shift + 8)) != (prefix >> (shift + 8))) continue;
                atomicAdd(&hist[wid][(key >> shift) & 255u], 1u);
            }
            __syncthreads();
            if (wid == 0) {
                const int b0 = lane * 4;
                unsigned h0 = 0, h1 = 0, h2 = 0, h3 = 0;
#pragma unroll
                for (int w = 0; w < 16; ++w) {
                    h0 += hist[w][b0]; h1 += hist[w][b0 + 1];
                    h2 += hist[w][b0 + 2]; h3 += hist[w][b0 + 3];
                }
                const unsigned loc = h0 + h1 + h2 + h3;
                unsigned ssum = loc;
#pragma unroll
                for (int o2 = 1; o2 < 64; o2 <<= 1) {
                    const unsigned t2 = __shfl_down(ssum, o2, 64);
                    if (lane + o2 < 64) ssum += t2;
                }
                const unsigned above = ssum - loc;
                const unsigned cum3 = above + h3;
                const unsigned cum2 = cum3 + h2;
                const unsigned cum1 = cum2 + h1;
                const unsigned cum0 = cum1 + h0;
                const unsigned long long msk = __ballot(cum0 >= (unsigned)r);
                if (msk == 0ULL) {
                    if (lane == 0) sh_flag = 1;
                } else {
                    const int L = 63 - __clzll(msk);
                    if (lane == L) {
                        unsigned selbin, cumsel, hsel;
                        if      (cum3 >= (unsigned)r) { selbin = b0 + 3; cumsel = cum3; hsel = h3; }
                        else if (cum2 >= (unsigned)r) { selbin = b0 + 2; cumsel = cum2; hsel = h2; }
                        else if (cum1 >= (unsigned)r) { selbin = b0 + 1; cumsel = cum1; hsel = h1; }
                        else                          { selbin = b0;     cumsel = cum0; hsel = h0; }
                        sh_prefix = prefix | (selbin << shift);
                        sh_r = (unsigned)r - (cumsel - hsel);
                        sh_flag = 0;
                    }
                }
            }
            __syncthreads();
            flag = sh_flag;
            if (flag) break;
            prefix = sh_prefix;
            r = (int)sh_r;
        }
        take_all = (flag != 0);
        if (!take_all) { Kstar = prefix; r_eq = r; }
    }

    float obj = 0.0f;
    if (k > 0) {
        for (int j = tid; j < PRI; j += 1024) {
            const unsigned key = keys_s[j];
            if (key != 0u && (take_all || key > Kstar))
                obj += __uint_as_float(key ^ 0x80000000u);
        }
        if (tid == 0 && !take_all)
            obj += (float)r_eq * __uint_as_float(Kstar ^ 0x80000000u);
    }

#pragma unroll
    for (int off = 32; off > 0; off >>= 1) obj += __shfl_xor(obj, off, 64);
    __syncthreads();
    if (lane == 0) fred[wid] = obj;
    __syncthreads();
    if (tid == 0) {
        float to = 0.0f;
#pragma unroll
        for (int w = 0; w < 16; ++w) to += fred[w];
        rowobj[row] = to;
        rownp[row]  = (float)num_pos;
    }
}

// ---------------------------------------------------------------------------
// Kernel 3: final reduction -> 2 scalars (NPERS + BATCH inputs, ~1 us)
// ---------------------------------------------------------------------------
__global__ __launch_bounds__(256) void k_final(const float* __restrict__ cepart,
                                               const float* __restrict__ slpart,
                                               const float* __restrict__ rowobj,
                                               const float* __restrict__ rownp,
                                               float* __restrict__ out) {
    const int tid = threadIdx.x;
    float ce = 0.0f, sl = 0.0f;
    for (int i = tid; i < NPERS; i += 256) { ce += cepart[i]; sl += slpart[i]; }
    float ro = 0.0f, np = 0.0f;
    if (tid < BATCH) { ro = rowobj[tid]; np = rownp[tid]; }
#pragma unroll
    for (int off = 32; off > 0; off >>= 1) {
        ce += __shfl_xor(ce, off, 64);
        sl += __shfl_xor(sl, off, 64);
        ro += __shfl_xor(ro, off, 64);
        np += __shfl_xor(np, off, 64);
    }
    __shared__ float r0[4], r1[4], r2[4], r3[4];
    const int wid = tid >> 6, lane = tid & 63;
    if (lane == 0) { r0[wid] = ce; r1[wid] = sl; r2[wid] = ro; r3[wid] = np; }
    __syncthreads();
    if (tid == 0) {
        const float tce = r0[0] + r0[1] + r0[2] + r0[3];
        const float tsl = r1[0] + r1[1] + r1[2] + r1[3];
        const float tro = r2[0] + r2[1] + r2[2] + r2[3];
        const float tnp = r3[0] + r3[1] + r3[2] + r3[3];
        const float npos = fmaxf(tnp, 1.0f);
        out[0] = (tce + tro) / npos;
        out[1] = tsl / npos;
    }
}

extern "C" void kernel_launch(void* const* d_in, const int* in_sizes, int n_in,
                              void* d_out, int out_size, void* d_ws, size_t ws_size,
                              hipStream_t stream) {
    const float* pred_loc  = (const float*)d_in[0];
    const float* pred_conf = (const float*)d_in[1];
    const float* gt_loc    = (const float*)d_in[2];
    const int*   gt_labels = (const int*)d_in[3];
    float* out = (float*)d_out;

    unsigned* keysg   = (unsigned*)d_ws;                  // NTOT u32
    float*    cepart  = (float*)(keysg + NTOT);           // NPERS f
    float*    slpart  = cepart + NPERS;                   // NPERS f
    float*    rowobj  = slpart + NPERS;                   // BATCH f
    float*    rownp   = rowobj + BATCH;                   // BATCH f

    k_lse<<<NPERS, 256, 0, stream>>>(pred_conf, gt_labels, pred_loc, gt_loc,
                                     keysg, cepart, slpart);
    k_row<<<BATCH, 1024, 0, stream>>>(keysg, rowobj, rownp);
    k_final<<<1, 256, 0, stream>>>(cepart, slpart, rowobj, rownp, out);
}